// Round 3
// baseline (286.166 us; speedup 1.0000x reference)
//
#include <hip/hip_runtime.h>

// TopologyNetwork: B=1024, N=5000, K=16, 9 levels.
// R16 = two-choice bank-matching with FAST near-max matching + latency fixes:
//  - k_pack5: greedy two-choice + 3 deterministic depth-1 AUGMENT passes
//    (move a blocking owner to its free alternate slot). Fully unrolled,
//    predicated, zero data-dependent loops (R15's serial cuckoo walk cost
//    +32us of pack time for barely-better matching). Expected unmatched
//    ~1.4/16 vs greedy's 4.8.
//  - k_fused: per-level edge+bias data lives in registers, prefetched one
//    level ahead (EA/EB ping-pong, ~160 VGPR; 4 waves/SIMD allows 512) ->
//    level-start L2-latency bubble removed. Write addresses (incl. sigma(n)
//    and parity base) hoisted out of the level loop.
//  - Layout unchanged from R15: copy A at slot s, copy B at 5008+sigma(s),
//    sigma(s)=(s&15)*313+(s>>4); read parity baked into packed slot.

#define TB 1024
#define TN 5000
#define TK 16
#define TLV 9
#define CPG 4                   // f16 cols per group (8 B per node-row)
#define NG  (TB / CPG)          // 256 col-groups = grid
#define LT  1024                // threads per block (16 waves)
#define PEL (TN * TK)           // u32 per level in packed-edge array

#define SLOTS_A 5008            // copy A occupies slots [0,5000), pad to x16
#define SLOTS   10016           // per parity: A + B copies
#define PSTRIDE (SLOTS * 8)     // 80128 B per parity

typedef unsigned int u32;
typedef unsigned short u16;
typedef _Float16 h2 __attribute__((ext_vector_type(2)));

__device__ __forceinline__ h2 u2h(u32 v) { return __builtin_bit_cast(h2, v); }
__device__ __forceinline__ u32 h2u(h2 h) { return __builtin_bit_cast(u32, h); }
__device__ __forceinline__ u32 packf(float a, float b) {
    h2 h; h.x = (_Float16)a; h.y = (_Float16)b;
    return h2u(h);
}
// injective remap for copy B; bank-pair sigma(s)&15 = (9*(s&15)+(s>>4))&15
__device__ __forceinline__ u32 sigma(u32 n) { return (n & 15u) * 313u + (n >> 4); }

// ---- pack + greedy + depth-1 augment matching ----
// One thread per (level,node). Edge at LDS slot o wants gather-step
// k = (class(o) - n) & 15 so the wave's 64 consecutive lanes hit each
// bank-pair exactly 4x (the ds_read_b64 floor). Two candidate slots per
// edge (copy A / copy B).
__global__ __launch_bounds__(256) void k_pack5(
    const int* __restrict__ idx, const float* __restrict__ w,
    u32* __restrict__ pe)
{
    __shared__ u32 sva[256][17];           // edge value via copy A
    __shared__ u32 svb[256][17];           // edge value via copy B
    __shared__ u32 sval[256][17];          // final value per gather-step
    __shared__ signed char  sown[256][17]; // step -> owning edge (-1 free)
    __shared__ unsigned char ska[256][17]; // kA | kB<<4 per edge

    const int t = threadIdx.x;
    const int j = blockIdx.x * 256 + t;    // (level,node) id
    const int NT = TLV * TN;               // 45000

    if (j < NT) {
        const u32 n     = (u32)(j % TN);
        const u32 l     = (u32)(j / TN);
        const u32 pbase = (l & 1u) * (u32)SLOTS;  // read-parity base (mod16==0)
        const int eb = j * TK;
        const int4*   ip = reinterpret_cast<const int4*>(idx + eb);
        const float4* wp = reinterpret_cast<const float4*>(w + eb);
        const int4   i0 = ip[0], i1 = ip[1], i2 = ip[2], i3 = ip[3];
        const float4 w0 = wp[0], w1 = wp[1], w2 = wp[2], w3 = wp[3];
        const int   si[TK] = {i0.x,i0.y,i0.z,i0.w, i1.x,i1.y,i1.z,i1.w,
                              i2.x,i2.y,i2.z,i2.w, i3.x,i3.y,i3.z,i3.w};
        const float wv[TK] = {w0.x,w0.y,w0.z,w0.w, w1.x,w1.y,w1.z,w1.w,
                              w2.x,w2.y,w2.z,w2.w, w3.x,w3.y,w3.z,w3.w};

        u32 ka_[TK], kb_[TK], va_[TK], vb_[TK];
        #pragma unroll
        for (int k = 0; k < TK; ++k) {
            const u32 s = (u32)si[k];
            const u32 sg = sigma(s);
            h2 hw; hw.x = (_Float16)wv[k]; hw.y = (_Float16)0.0f;
            const u32 wb = h2u(hw) << 16;              // f16 weight, high 16
            va_[k] = (pbase + s) | wb;                 // 15-bit slot_full
            vb_[k] = (pbase + SLOTS_A + sg) | wb;
            ka_[k] = (s - n) & 15u;
            kb_[k] = (sg - n) & 15u;
            sva[t][k] = va_[k];
            svb[t][k] = vb_[k];
            ska[t][k] = (unsigned char)(ka_[k] | (kb_[k] << 4));
        }
        #pragma unroll
        for (int k = 0; k < TK; ++k) sown[t][k] = (signed char)-1;

        // greedy two-choice
        u32 used = 0, pend = 0;
        #pragma unroll
        for (int k = 0; k < TK; ++k) {
            const u32 a = ka_[k], b = kb_[k];
            if (!((used >> a) & 1u)) {
                used |= 1u << a; sown[t][a] = (signed char)k; sval[t][a] = va_[k];
            } else if (!((used >> b) & 1u)) {
                used |= 1u << b; sown[t][b] = (signed char)k; sval[t][b] = vb_[k];
            } else pend |= 1u << k;
        }

        // 3 depth-1 augment passes: move a blocking owner to its free alt
        #pragma unroll
        for (int pass = 0; pass < 3; ++pass) {
            #pragma unroll
            for (int k = 0; k < TK; ++k) {
                if ((pend >> k) & 1u) {
                    bool done = false;
                    {   // via copy A's step
                        const u32 s = ka_[k];
                        const int o = sown[t][s];
                        if (o >= 0) {
                            const u32 ca = (u32)ska[t][o];
                            const u32 oa = ca & 15u, ob = ca >> 4;
                            const u32 alt = (s == oa) ? ob : oa;
                            if (!((used >> alt) & 1u)) {
                                used |= 1u << alt;
                                sown[t][alt] = (signed char)o;
                                sval[t][alt] = (alt == oa) ? sva[t][o] : svb[t][o];
                                sown[t][s] = (signed char)k; sval[t][s] = va_[k];
                                pend &= ~(1u << k); done = true;
                            }
                        } else {   // defensive: free slot -> take it
                            used |= 1u << s;
                            sown[t][s] = (signed char)k; sval[t][s] = va_[k];
                            pend &= ~(1u << k); done = true;
                        }
                    }
                    if (!done) {   // via copy B's step
                        const u32 s = kb_[k];
                        const int o = sown[t][s];
                        if (o >= 0) {
                            const u32 ca = (u32)ska[t][o];
                            const u32 oa = ca & 15u, ob = ca >> 4;
                            const u32 alt = (s == oa) ? ob : oa;
                            if (!((used >> alt) & 1u)) {
                                used |= 1u << alt;
                                sown[t][alt] = (signed char)o;
                                sval[t][alt] = (alt == oa) ? sva[t][o] : svb[t][o];
                                sown[t][s] = (signed char)k; sval[t][s] = vb_[k];
                                pend &= ~(1u << k);
                            }
                        } else {
                            used |= 1u << s;
                            sown[t][s] = (signed char)k; sval[t][s] = vb_[k];
                            pend &= ~(1u << k);
                        }
                    }
                }
            }
        }

        // fallback: few unmatched -> lowest free step (copy A)
        #pragma unroll
        for (int k = 0; k < TK; ++k) {
            if ((pend >> k) & 1u) {
                const u32 slot = (u32)__builtin_ctz(~used);
                used |= 1u << slot;
                sval[t][slot] = va_[k];
            }
        }
    }
    __syncthreads();

    // coalesced write-out of the block's 256 nodes x 16 steps
    const int jb    = blockIdx.x * 256;
    const int nodeN = min(256, NT - jb);
    const int elems = nodeN * TK;
    for (int p = t; p < elems; p += 256)
        pe[(size_t)jb * TK + p] = sval[p >> 4][p & 15];
}

// ---- fused: transpose-in + 9 levels in LDS + transpose-out ----
// One level body: optionally prefetch next level's edges+biases into the
// other register set, then gather+fma+write from the current set.
#define LVL(EC, bC, EN, bN, PRE, LNEXT, WA, WB) do {                          \
    if (PRE) {                                                                \
        const u32*   epn = pe + (size_t)(LNEXT) * PEL;                        \
        const float* bn  = biases + (size_t)(LNEXT) * TN;                     \
        _Pragma("unroll")                                                     \
        for (int it = 0; it < 5; ++it) if (it < 4 || t4) {                    \
            const uint4* p = reinterpret_cast<const uint4*>(                  \
                epn + (size_t)(t + it * LT) * TK);                            \
            EN[it][0] = p[0]; EN[it][1] = p[1];                               \
            EN[it][2] = p[2]; EN[it][3] = p[3];                               \
            bN[it] = bn[t + it * LT];                                         \
        }                                                                     \
    }                                                                         \
    _Pragma("unroll")                                                         \
    for (int it = 0; it < 5; ++it) if (it < 4 || t4) {                        \
        const u32 es[TK] = {EC[it][0].x, EC[it][0].y, EC[it][0].z, EC[it][0].w,\
                            EC[it][1].x, EC[it][1].y, EC[it][1].z, EC[it][1].w,\
                            EC[it][2].x, EC[it][2].y, EC[it][2].z, EC[it][2].w,\
                            EC[it][3].x, EC[it][3].y, EC[it][3].z, EC[it][3].w};\
        u32 a01 = packf(bC[it], bC[it]);                                      \
        u32 a23 = a01;                                                        \
        _Pragma("unroll")                                                     \
        for (int k = 0; k < TK; ++k) {                                        \
            const u32 e   = es[k];                                            \
            const u32 off = (u32)(u16)e << 3;       /* slot_full*8 */         \
            const uint2 av = *reinterpret_cast<const uint2*>(lds + off);      \
            asm("v_pk_fma_f16 %0, %1, %2, %0 op_sel:[1,0,0] op_sel_hi:[1,1,1]"\
                : "+v"(a01) : "v"(e), "v"(av.x));                             \
            asm("v_pk_fma_f16 %0, %1, %2, %0 op_sel:[1,0,0] op_sel_hi:[1,1,1]"\
                : "+v"(a23) : "v"(e), "v"(av.y));                             \
        }                                                                     \
        h2 A = u2h(a01), Bv = u2h(a23);                                       \
        h2 tenth; tenth.x = (_Float16)0.1f; tenth.y = (_Float16)0.1f;         \
        A  = __builtin_elementwise_max(A,  A  * tenth);                       \
        Bv = __builtin_elementwise_max(Bv, Bv * tenth);                       \
        uint2 r; r.x = h2u(A); r.y = h2u(Bv);                                 \
        *reinterpret_cast<uint2*>(lds + WA[it]) = r;                          \
        *reinterpret_cast<uint2*>(lds + WB[it]) = r;                          \
    }                                                                         \
    __syncthreads();                                                          \
} while (0)

__global__ __launch_bounds__(LT) void k_fused(
    const float* __restrict__ x,      // [B,N]
    float* __restrict__ out,          // [B,N]
    const u32* __restrict__ pe,       // [LV][TN][TK] (slot_full | f16w<<16)
    const float* __restrict__ biases) // [LV][TN]
{
    __shared__ char lds[2 * PSTRIDE]; // ping-pong parities, each A+B copies
    const int g = blockIdx.x;
    const int t = threadIdx.x;
    const bool t4 = (t + 4 * LT) < TN;

    // hoisted per-iteration write/read byte offsets (both parities)
    u32 offA0[5], offB0[5], offA1[5], offB1[5];
    #pragma unroll
    for (int it = 0; it < 5; ++it) {
        const u32 n = (u32)(t + it * LT);
        const u32 a = n * 8u;
        const u32 b = (u32)(SLOTS_A + sigma(n)) * 8u;  // garbage for invalid
        offA0[it] = a;            offB0[it] = b;        // lanes, never used
        offA1[it] = a + PSTRIDE;  offB1[it] = b + PSTRIDE;
    }

    uint4 EA[5][4], EB[5][4];
    float bA[5], bB[5];

    // prefetch level 0 edges + biases (overlaps staging loads below)
    {
        const u32* ep0 = pe;
        #pragma unroll
        for (int it = 0; it < 5; ++it) if (it < 4 || t4) {
            const uint4* p = reinterpret_cast<const uint4*>(
                ep0 + (size_t)(t + it * LT) * TK);
            EA[it][0] = p[0]; EA[it][1] = p[1];
            EA[it][2] = p[2]; EA[it][3] = p[3];
            bA[it] = biases[t + it * LT];
        }
    }

    // stage x cols g*4..g*4+3 as f16 rows into parity 0, both copies
    {
        const float* xp0 = x + (size_t)(g * CPG + 0) * TN;
        const float* xp1 = x + (size_t)(g * CPG + 1) * TN;
        const float* xp2 = x + (size_t)(g * CPG + 2) * TN;
        const float* xp3 = x + (size_t)(g * CPG + 3) * TN;
        #pragma unroll
        for (int it = 0; it < 5; ++it) if (it < 4 || t4) {
            const int n = t + it * LT;
            uint2 v;
            v.x = packf(xp0[n], xp1[n]);
            v.y = packf(xp2[n], xp3[n]);
            *reinterpret_cast<uint2*>(lds + offA0[it]) = v;
            *reinterpret_cast<uint2*>(lds + offB0[it]) = v;
        }
    }
    __syncthreads();

    // 9 levels: even level reads parity 0/writes 1, odd reads 1/writes 0.
    #pragma unroll 1
    for (int lp = 0; lp < 4; ++lp) {
        LVL(EA, bA, EB, bB, true, (2 * lp + 1), offA1, offB1); // even level
        LVL(EB, bB, EA, bA, true, (2 * lp + 2), offA0, offB0); // odd level
    }
    LVL(EA, bA, EB, bB, false, 0, offA1, offB1);               // level 8

    // write out cols g*4..g*4+3 (copy A of parity 1)
    {
        float* op0 = out + (size_t)(g * CPG + 0) * TN;
        float* op1 = out + (size_t)(g * CPG + 1) * TN;
        float* op2 = out + (size_t)(g * CPG + 2) * TN;
        float* op3 = out + (size_t)(g * CPG + 3) * TN;
        #pragma unroll
        for (int it = 0; it < 5; ++it) if (it < 4 || t4) {
            const int n = t + it * LT;
            const uint2 v = *reinterpret_cast<const uint2*>(lds + offA1[it]);
            h2 h;
            h = u2h(v.x); op0[n] = (float)h.x; op1[n] = (float)h.y;
            h = u2h(v.y); op2[n] = (float)h.x; op3[n] = (float)h.y;
        }
    }
}

extern "C" void kernel_launch(void* const* d_in, const int* in_sizes, int n_in,
                              void* d_out, int out_size, void* d_ws, size_t ws_size,
                              hipStream_t stream)
{
    const float* x       = (const float*)d_in[0];   // [B,N]
    const int*   src_idx = (const int*)  d_in[1];   // [LV,N,K]
    const float* weights = (const float*)d_in[2];   // [LV,N,K]
    const float* biases  = (const float*)d_in[3];   // [LV,N]
    float* out = (float*)d_out;                     // [B,N]

    u32* pe = (u32*)d_ws;                           // [LV][TN][TK] = 2.88 MB

    // pack + greedy/augment slot matching
    {
        const int nn = TLV * TN;                    // 45000 nodes
        hipLaunchKernelGGL(k_pack5, dim3((nn + 255) / 256), dim3(256), 0, stream,
                           src_idx, weights, pe);
    }
    // fused 9-level evaluation
    hipLaunchKernelGGL(k_fused, dim3(NG), dim3(LT), 0, stream,
                       x, out, pe, biases);
}

// Round 4
// 135.038 us; speedup vs baseline: 2.1191x; 2.1191x over previous
//
#include <hip/hip_runtime.h>

// TopologyNetwork: B=1024, N=5000, K=16, 9 levels.
// R17: back to R13's simple single-copy layout + software-pipelined edge loads.
//  - Matching/copy-B ABANDONED: R13(1.45e7 conf)=60-62us, R15(1.0e7)=62us ->
//    bank conflicts are not the critical path; they hide under issue/latency.
//  - k_pack: trivial elementwise. Packed edge = slot_full | f16(w)<<16 with
//    read parity (l&1)*5056 baked in -> constant LDS base, 2 VALU/edge.
//    Biases pre-packed to f16x2 (b2) -> no per-node cvt in fused.
//  - k_fused: per-level loop with TWO named register sets (P/Q) rolling
//    prefetch: iteration i+1's 4x dwordx4 edge loads + bias issue while
//    iteration i computes; next level's iter-0 issues before the barrier.
//    All named scalars, no arrays (R16's 5-deep arrays went to scratch:
//    FETCH 22->220 GB). ~80 VGPR, 16 waves/CU.

#define TB 1024
#define TN 5000
#define TK 16
#define TLV 9
#define CPG 4                   // f16 cols per group (8 B per node-row)
#define NG  (TB / CPG)          // 256 col-groups = grid
#define LT  1024                // threads per block (16 waves)
#define PEL (TN * TK)           // u32 per level in packed-edge array

#define SLOTP 5056              // slots per parity (pad 5000 -> x16)
#define PSTRIDE (SLOTP * 8)     // 40448 B per parity; total LDS 80896 B
#define WOFF_IT 8192            // per-iteration write offset step (1024*8)

typedef unsigned int u32;
typedef unsigned short u16;
typedef _Float16 h2 __attribute__((ext_vector_type(2)));

__device__ __forceinline__ h2 u2h(u32 v) { return __builtin_bit_cast(h2, v); }
__device__ __forceinline__ u32 h2u(h2 h) { return __builtin_bit_cast(u32, h); }
__device__ __forceinline__ u32 packf(float a, float b) {
    h2 h; h.x = (_Float16)a; h.y = (_Float16)b;
    return h2u(h);
}

// ---- pack: elementwise, fully coalesced ----
// pe[j] = ((l&1)*SLOTP + s) | f16(w)<<16 ; b2[l*TN+n] = packf(bias,bias)
__global__ __launch_bounds__(256) void k_pack(
    const int* __restrict__ idx, const float* __restrict__ w,
    const float* __restrict__ biases,
    u32* __restrict__ pe, u32* __restrict__ b2)
{
    const int j = blockIdx.x * 256 + threadIdx.x;
    if (j < TLV * TN * TK) {
        const int l = j / (TN * TK);
        const u32 s = (u32)idx[j];
        h2 hw; hw.x = (_Float16)w[j]; hw.y = (_Float16)0.0f;
        pe[j] = ((u32)(l & 1) * (u32)SLOTP + s) | (h2u(hw) << 16);
    }
    if (j < TLV * TN) {
        const float b = biases[j];
        b2[j] = packf(b, b);
    }
}

// ---- fused: transpose-in + 9 pipelined levels in LDS + transpose-out ----

// prefetch node (LL, t + IT*LT) edges + packed bias into register set S
#define PREF(S, LL, IT) do {                                                  \
    const size_t _n = (size_t)(LL) * TN + (size_t)(t + (IT) * LT);            \
    const uint4* _p = reinterpret_cast<const uint4*>(pe + _n * TK);           \
    S##a = _p[0]; S##b = _p[1]; S##c = _p[2]; S##d = _p[3];                   \
    S##i = b2[_n];                                                            \
} while (0)

#define EDGE(EV) do {                                                         \
    const u32 _e   = (EV);                                                    \
    const u32 _off = (_e & 0xffffu) << 3;          /* slot_full*8 bytes */    \
    const uint2 _av = *reinterpret_cast<const uint2*>(lds + _off);            \
    asm("v_pk_fma_f16 %0, %1, %2, %0 op_sel:[1,0,0] op_sel_hi:[1,1,1]"        \
        : "+v"(a01) : "v"(_e), "v"(_av.x));                                   \
    asm("v_pk_fma_f16 %0, %1, %2, %0 op_sel:[1,0,0] op_sel_hi:[1,1,1]"        \
        : "+v"(a23) : "v"(_e), "v"(_av.y));                                   \
} while (0)

// consume register set S for iteration IT, write result to LDS
#define COMP(S, WBASE, IT) do {                                               \
    u32 a01 = S##i, a23 = S##i;                    /* bias in both halves */  \
    EDGE(S##a.x); EDGE(S##a.y); EDGE(S##a.z); EDGE(S##a.w);                   \
    EDGE(S##b.x); EDGE(S##b.y); EDGE(S##b.z); EDGE(S##b.w);                   \
    EDGE(S##c.x); EDGE(S##c.y); EDGE(S##c.z); EDGE(S##c.w);                   \
    EDGE(S##d.x); EDGE(S##d.y); EDGE(S##d.z); EDGE(S##d.w);                   \
    h2 A = u2h(a01), Bv = u2h(a23);                                           \
    h2 tenth; tenth.x = (_Float16)0.1f; tenth.y = (_Float16)0.1f;             \
    A  = __builtin_elementwise_max(A,  A  * tenth);                           \
    Bv = __builtin_elementwise_max(Bv, Bv * tenth);                           \
    uint2 _r; _r.x = h2u(A); _r.y = h2u(Bv);                                  \
    *reinterpret_cast<uint2*>(lds + (WBASE) + (IT) * WOFF_IT) = _r;           \
} while (0)

// one level: rolling prefetch; next level's iter-0 issues pre-barrier.
// Entering: S0 holds (LL, it=0). Exiting: S1 holds (LL+1, it=0).
#define LVL(LL, S0, S1, WBASE, LAST) do {                                     \
    PREF(S1, (LL), 1); COMP(S0, WBASE, 0);                                    \
    PREF(S0, (LL), 2); COMP(S1, WBASE, 1);                                    \
    PREF(S1, (LL), 3); COMP(S0, WBASE, 2);                                    \
    if (t4) PREF(S0, (LL), 4);                                                \
    COMP(S1, WBASE, 3);                                                       \
    if (!(LAST)) PREF(S1, (LL) + 1, 0);                                       \
    if (t4) COMP(S0, WBASE, 4);                                               \
    __syncthreads();                                                          \
} while (0)

__global__ __launch_bounds__(LT) void k_fused(
    const float* __restrict__ x,      // [B,N]
    float* __restrict__ out,          // [B,N]
    const u32* __restrict__ pe,       // [LV][TN][TK] (slot_full | f16w<<16)
    const u32* __restrict__ b2)       // [LV][TN] packed f16x2 biases
{
    __shared__ char lds[2 * PSTRIDE]; // ping-pong parities, single copy each
    const int g = blockIdx.x;
    const int t = threadIdx.x;
    const bool t4 = t < (TN - 4 * LT);       // t < 904
    const u32 woO = (u32)t * 8u;             // parity-0 write base
    const u32 woE = (u32)(SLOTP + t) * 8u;   // parity-1 write base

    uint4 Pa, Pb, Pc, Pd; u32 Pi;
    uint4 Qa, Qb, Qc, Qd; u32 Qi;

    // issue level-0 iter-0 edge loads first (hide under x staging)
    PREF(P, 0, 0);

    // stage x cols g*4..g*4+3 as f16 rows into parity 0
    {
        const float* xp0 = x + (size_t)(g * CPG + 0) * TN;
        const float* xp1 = x + (size_t)(g * CPG + 1) * TN;
        const float* xp2 = x + (size_t)(g * CPG + 2) * TN;
        const float* xp3 = x + (size_t)(g * CPG + 3) * TN;
        #pragma unroll
        for (int it = 0; it < 4; ++it) {
            const int n = t + it * LT;
            uint2 v;
            v.x = packf(xp0[n], xp1[n]);
            v.y = packf(xp2[n], xp3[n]);
            *reinterpret_cast<uint2*>(lds + woO + it * WOFF_IT) = v;
        }
        if (t4) {
            const int n = t + 4 * LT;
            uint2 v;
            v.x = packf(xp0[n], xp1[n]);
            v.y = packf(xp2[n], xp3[n]);
            *reinterpret_cast<uint2*>(lds + woO + 4 * WOFF_IT) = v;
        }
    }
    __syncthreads();

    // levels 0..7 (pairs keep P/Q alternation consistent), then level 8
    #pragma unroll 1
    for (int lp = 0; lp < 4; ++lp) {
        LVL(2 * lp,     P, Q, woE, false);   // even: read par0, write par1
        LVL(2 * lp + 1, Q, P, woO, false);   // odd:  read par1, write par0
    }
    LVL(8, P, Q, woE, true);                 // level 8 writes parity 1

    // write out cols g*4..g*4+3 (parity 1)
    {
        float* op0 = out + (size_t)(g * CPG + 0) * TN;
        float* op1 = out + (size_t)(g * CPG + 1) * TN;
        float* op2 = out + (size_t)(g * CPG + 2) * TN;
        float* op3 = out + (size_t)(g * CPG + 3) * TN;
        #pragma unroll
        for (int it = 0; it < 4; ++it) {
            const int n = t + it * LT;
            const uint2 v = *reinterpret_cast<const uint2*>(lds + woE + it * WOFF_IT);
            h2 h;
            h = u2h(v.x); op0[n] = (float)h.x; op1[n] = (float)h.y;
            h = u2h(v.y); op2[n] = (float)h.x; op3[n] = (float)h.y;
        }
        if (t4) {
            const int n = t + 4 * LT;
            const uint2 v = *reinterpret_cast<const uint2*>(lds + woE + 4 * WOFF_IT);
            h2 h;
            h = u2h(v.x); op0[n] = (float)h.x; op1[n] = (float)h.y;
            h = u2h(v.y); op2[n] = (float)h.x; op3[n] = (float)h.y;
        }
    }
}

extern "C" void kernel_launch(void* const* d_in, const int* in_sizes, int n_in,
                              void* d_out, int out_size, void* d_ws, size_t ws_size,
                              hipStream_t stream)
{
    const float* x       = (const float*)d_in[0];   // [B,N]
    const int*   src_idx = (const int*)  d_in[1];   // [LV,N,K]
    const float* weights = (const float*)d_in[2];   // [LV,N,K]
    const float* biases  = (const float*)d_in[3];   // [LV,N]
    float* out = (float*)d_out;                     // [B,N]

    u32* pe = (u32*)d_ws;                           // [LV][TN][TK] = 2.88 MB
    u32* b2 = pe + (size_t)TLV * TN * TK;           // [LV][TN]     = 180 KB

    // pack (elementwise, fully coalesced)
    {
        const int ne = TLV * TN * TK;               // 720000
        hipLaunchKernelGGL(k_pack, dim3((ne + 255) / 256), dim3(256), 0, stream,
                           src_idx, weights, biases, pe, b2);
    }
    // fused 9-level evaluation
    hipLaunchKernelGGL(k_fused, dim3(NG), dim3(LT), 0, stream,
                       x, out, pe, b2);
}